// Round 3
// baseline (339.140 us; speedup 1.0000x reference)
//
#include <hip/hip_runtime.h>
#include <stdint.h>
#include <math.h>

#define NB 32  // batch

// ---------------- Threefry-2x32-20 (exact JAX semantics) ----------------
__device__ __forceinline__ void tf_block(uint32_t k0, uint32_t k1, uint32_t& x0, uint32_t& x1) {
  uint32_t k2 = 0x1BD11BDAu ^ k0 ^ k1;
  x0 += k0; x1 += k1;
#define TFR(r) { x0 += x1; x1 = (x1 << r) | (x1 >> (32 - r)); x1 ^= x0; }
  TFR(13) TFR(15) TFR(26) TFR(6)
  x0 += k1; x1 += k2 + 1u;
  TFR(17) TFR(29) TFR(16) TFR(24)
  x0 += k2; x1 += k0 + 2u;
  TFR(13) TFR(15) TFR(26) TFR(6)
  x0 += k0; x1 += k1 + 3u;
  TFR(17) TFR(29) TFR(16) TFR(24)
  x0 += k1; x1 += k2 + 4u;
  TFR(13) TFR(15) TFR(26) TFR(6)
  x0 += k2; x1 += k0 + 5u;
#undef TFR
}

__device__ __forceinline__ float sigmoidf(float x) { return 1.0f / (1.0f + expf(-x)); }

__device__ __forceinline__ float wave_reduce(float v) {
  for (int o = 32; o > 0; o >>= 1) v += __shfl_down(v, o, 64);
  return v;
}

// ---------------- K0: perms + zero the slot accumulators ----------------
__global__ __launch_bounds__(256) void k0_perm(int* idx0, int* idx1, float* ws) {
  __shared__ uint32_t sub[2][2];
  __shared__ uint32_t bits[2][256];
  int t = threadIdx.x;
  for (int i = t; i < 384; i += 256) ws[i] = 0.0f;  // slots + main acc
  if (t == 0) {
    for (int i = 0; i < 2; ++i) {
      uint32_t f0 = 0u, f1 = (uint32_t)i;          // fold_in(key(42), i)
      tf_block(0u, 42u, f0, f1);
      uint32_t a0 = 0u, a1 = 2u; tf_block(f0, f1, a0, a1);   // split -> kt = (e02.x1, e13.x1)
      uint32_t b0 = 1u, b1 = 3u; tf_block(f0, f1, b0, b1);
      uint32_t kt0 = a1, kt1 = b1;
      uint32_t c0 = 0u, c1 = 2u; tf_block(kt0, kt1, c0, c1); // split inside permutation
      uint32_t d0 = 1u, d1 = 3u; tf_block(kt0, kt1, d0, d1);
      sub[i][0] = c1; sub[i][1] = d1;
    }
  }
  __syncthreads();
  if (t < 128) {
    for (int i = 0; i < 2; ++i) {
      uint32_t x0 = (uint32_t)t, x1 = (uint32_t)(t + 128);
      tf_block(sub[i][0], sub[i][1], x0, x1);
      bits[i][t] = x0; bits[i][t + 128] = x1;
    }
  }
  __syncthreads();
  for (int i = 0; i < 2; ++i) {   // stable ascending rank = lax.sort_key_val
    uint32_t mine = bits[i][t];
    int rank = 0;
    for (int k = 0; k < 256; ++k) {
      uint32_t v = bits[i][k];
      rank += (v < mine) || (v == mine && k < t);
    }
    int lim = (i == 0) ? 64 : 128;
    if (rank < lim) { (i == 0 ? idx0 : idx1)[rank] = t; }
  }
}

// ---------------- K1: fused pass1 (plane ssq + SCR MSE), wave-granular ----------------
// grid: [0,2048) feat0 block/plane; [2048,3072) feat1 wave/plane; [3072,3584) feat2 wave/4planes
__global__ __launch_bounds__(256) void k1_pass1(
    const float* __restrict__ f0, const float* __restrict__ f1, const float* __restrict__ f2,
    const int* __restrict__ idx0, const int* __restrict__ idx1,
    float* __restrict__ ns0, float* __restrict__ ns1, float* __restrict__ ns2,
    float* __restrict__ scr0_s, float* __restrict__ scr1_s) {
  __shared__ float tpl[4096];   // up to 4 teacher planes (16 KB)
  __shared__ float red[8];
  int bid = blockIdx.x;
  int lane = threadIdx.x & 63, wv = threadIdx.x >> 6;
  if (bid < 2048) {
    // feat0: one 128x128 plane per block; wave wv owns quarter wv
    int b = bid >> 6, c = bid & 63;
    int tc = idx0[c];
    ((float4*)tpl)[threadIdx.x] = ((const float4*)(f2 + ((size_t)b * 256 + tc) * 1024))[threadIdx.x];
    __syncthreads();
    const float4* plane = (const float4*)(f0 + (size_t)bid * 16384);
    float ssq = 0.f, scr = 0.f;
#pragma unroll 8
    for (int it = 0; it < 16; ++it) {
      int p = (wv * 16 + it) * 64 + lane;
      float4 v = plane[p];
      int pix = p * 4, h = pix >> 7, w = pix & 127;
      float tv = tpl[(h >> 2) * 32 + (w >> 2)];   // w%4==0 -> all 4 px same cell
      ssq += v.x * v.x + v.y * v.y + v.z * v.z + v.w * v.w;
      float dx = v.x - tv, dy = v.y - tv, dz = v.z - tv, dw = v.w - tv;
      scr += dx * dx + dy * dy + dz * dz + dw * dw;
    }
    ssq = wave_reduce(ssq); scr = wave_reduce(scr);
    if (lane == 0) { red[wv] = ssq; red[4 + wv] = scr; }
    __syncthreads();
    if (threadIdx.x == 0) {
      ns0[bid] = red[0] + red[1] + red[2] + red[3];
      atomicAdd(&scr0_s[bid & 63], red[4] + red[5] + red[6] + red[7]);
    }
  } else if (bid < 3072) {
    // feat1: wave per 64x64 plane
    int unit = ((bid - 2048) << 2) + wv;   // 0..4095
    int b = unit >> 7, c = unit & 127;
    int tc = idx1[c];
    const float4* tp = (const float4*)(f2 + ((size_t)b * 256 + tc) * 1024);
#pragma unroll
    for (int it = 0; it < 4; ++it)
      ((float4*)tpl)[(wv << 8) + it * 64 + lane] = tp[it * 64 + lane];
    __syncthreads();
    const float* mytpl = tpl + (wv << 10);
    const float4* plane = (const float4*)(f1 + (size_t)unit * 4096);
    float ssq = 0.f, scr = 0.f;
#pragma unroll 8
    for (int it = 0; it < 16; ++it) {
      int p = it * 64 + lane;
      float4 v = plane[p];
      int pix = p * 4, h = pix >> 6, w = pix & 63;
      int tb = (h >> 1) * 32 + (w >> 1);
      float t0 = mytpl[tb], t1 = mytpl[tb + 1];   // w%4==0: x,y->t0  z,w->t1
      ssq += v.x * v.x + v.y * v.y + v.z * v.z + v.w * v.w;
      float dx = v.x - t0, dy = v.y - t0, dz = v.z - t1, dw = v.w - t1;
      scr += dx * dx + dy * dy + dz * dz + dw * dw;
    }
    ssq = wave_reduce(ssq); scr = wave_reduce(scr);
    if (lane == 0) {
      ns1[unit] = ssq;
      atomicAdd(&scr1_s[unit & 63], scr);
    }
  } else {
    // feat2: wave per 4 consecutive 32x32 planes
    int u4 = ((bid - 3072) << 2) + wv;     // 0..2047
    int p0 = u4 << 2;                      // 0..8188
#pragma unroll
    for (int j = 0; j < 4; ++j) {
      const float4* plane = (const float4*)(f2 + (size_t)(p0 + j) * 1024);
      float ssq = 0.f;
#pragma unroll
      for (int it = 0; it < 4; ++it) {
        float4 v = plane[it * 64 + lane];
        ssq += v.x * v.x + v.y * v.y + v.z * v.z + v.w * v.w;
      }
      ssq = wave_reduce(ssq);
      if (lane == 0) ns2[p0 + j] = ssq;
    }
  }
}

// ---------------- K2: ranks (stable descending) + main loss ----------------
template<int C>
__device__ __forceinline__ void rank_work(const float* __restrict__ normsq,
                                          float* __restrict__ flags, int b, float* nm) {
  for (int c = threadIdx.x; c < C; c += 256) nm[c] = sqrtf(normsq[b * C + c]);
  __syncthreads();
  for (int c = threadIdx.x; c < C; c += 256) {
    float mine = nm[c];
    int rank = 0;
    for (int k = 0; k < C; ++k) {
      float v = nm[k];
      rank += (v > mine) || (v == mine && k < c);
    }
    flags[b * C + c] = (rank < C / 2) ? 1.0f : 0.0f;
  }
}

__device__ __forceinline__ void main_work(const float* __restrict__ pred,
                                          const int* __restrict__ target,
                                          float* acc, int b, float* sh) {
  int t = threadIdx.x;
  const float* row = pred + b * 1000;
  float m = -INFINITY;
  for (int j = t; j < 1000; j += 256) m = fmaxf(m, row[j]);
  sh[t] = m; __syncthreads();
  for (int s = 128; s > 0; s >>= 1) { if (t < s) sh[t] = fmaxf(sh[t], sh[t + s]); __syncthreads(); }
  m = sh[0]; __syncthreads();
  float e = 0.f;
  for (int j = t; j < 1000; j += 256) e += expf(row[j] - m);
  sh[t] = e; __syncthreads();
  for (int s = 128; s > 0; s >>= 1) { if (t < s) sh[t] += sh[t + s]; __syncthreads(); }
  if (t == 0) atomicAdd(acc, (logf(sh[0]) + m - row[target[b]]) * (1.0f / 32.0f));
}

__global__ __launch_bounds__(256) void k2_rank_main(
    const float* __restrict__ ns0, const float* __restrict__ ns1, const float* __restrict__ ns2,
    float* __restrict__ fl0, float* __restrict__ fl1, float* __restrict__ fl2,
    const float* __restrict__ pred, const int* __restrict__ target, float* main_acc) {
  __shared__ float sh[256];
  int bid = blockIdx.x;
  if (bid < 32)       rank_work<64 >(ns0, fl0, bid,      sh);
  else if (bid < 64)  rank_work<128>(ns1, fl1, bid - 32, sh);
  else if (bid < 96)  rank_work<256>(ns2, fl2, bid - 64, sh);
  else                main_work(pred, target, main_acc, bid - 96, sh);
}

// ---------------- K3: fused pass2 (IFD), wave-granular ----------------
// grid: [0,512) feat0 (2048 wave units); [512,640) feat1 (512 units); [640,768) feat2 (512 units)
__global__ __launch_bounds__(256) void k3_pass2(
    const float* __restrict__ f0, const float* __restrict__ f1, const float* __restrict__ f2,
    const float* __restrict__ fl0, const float* __restrict__ fl1, const float* __restrict__ fl2,
    float* __restrict__ ifd0_s, float* __restrict__ ifd1_s, float* __restrict__ ifd2_s) {
  __shared__ float fls[1024];   // 4 waves x up to 256 flags
  int bid = blockIdx.x;
  int lane = threadIdx.x & 63, wv = threadIdx.x >> 6;
  if (bid < 512) {
    int unit = (bid << 2) + wv;            // 0..2047
    int b = unit >> 6, chunk = unit & 63;  // 64 chunks of 256 px
    float* fl = fls + (wv << 8);
    fl[lane] = fl0[(b << 6) + lane];       // 64 flags
    const float* base = f0 + (size_t)b * 64 * 16384 + (size_t)chunk * 256;
    float4 tot = {0, 0, 0, 0}, str = {0, 0, 0, 0};
#pragma unroll 8
    for (int c = 0; c < 64; ++c) {
      float4 v = ((const float4*)(base + (size_t)c * 16384))[lane];
      float f = fl[c];
      tot.x += v.x; tot.y += v.y; tot.z += v.z; tot.w += v.w;
      str.x = fmaf(v.x, f, str.x); str.y = fmaf(v.y, f, str.y);
      str.z = fmaf(v.z, f, str.z); str.w = fmaf(v.w, f, str.w);
    }
    const float ih = 1.0f / 32.0f;
    float s = 0.f, d;
    d = sigmoidf((tot.x - str.x) * ih) - sigmoidf(str.x * ih); s += d * d;
    d = sigmoidf((tot.y - str.y) * ih) - sigmoidf(str.y * ih); s += d * d;
    d = sigmoidf((tot.z - str.z) * ih) - sigmoidf(str.z * ih); s += d * d;
    d = sigmoidf((tot.w - str.w) * ih) - sigmoidf(str.w * ih); s += d * d;
    s = wave_reduce(s);
    if (lane == 0) atomicAdd(&ifd0_s[unit & 63], s);
  } else if (bid < 640) {
    int unit = ((bid - 512) << 2) + wv;    // 0..511
    int b = unit >> 4, chunk = unit & 15;  // 16 chunks of 256 px
    float* fl = fls + (wv << 8);
    fl[lane] = fl1[(b << 7) + lane];
    fl[64 + lane] = fl1[(b << 7) + 64 + lane];
    const float* base = f1 + (size_t)b * 128 * 4096 + (size_t)chunk * 256;
    float4 tot = {0, 0, 0, 0}, str = {0, 0, 0, 0};
#pragma unroll 8
    for (int c = 0; c < 128; ++c) {
      float4 v = ((const float4*)(base + (size_t)c * 4096))[lane];
      float f = fl[c];
      tot.x += v.x; tot.y += v.y; tot.z += v.z; tot.w += v.w;
      str.x = fmaf(v.x, f, str.x); str.y = fmaf(v.y, f, str.y);
      str.z = fmaf(v.z, f, str.z); str.w = fmaf(v.w, f, str.w);
    }
    const float ih = 1.0f / 64.0f;
    float s = 0.f, d;
    d = sigmoidf((tot.x - str.x) * ih) - sigmoidf(str.x * ih); s += d * d;
    d = sigmoidf((tot.y - str.y) * ih) - sigmoidf(str.y * ih); s += d * d;
    d = sigmoidf((tot.z - str.z) * ih) - sigmoidf(str.z * ih); s += d * d;
    d = sigmoidf((tot.w - str.w) * ih) - sigmoidf(str.w * ih); s += d * d;
    s = wave_reduce(s);
    if (lane == 0) atomicAdd(&ifd1_s[unit & 63], s);
  } else {
    int unit = ((bid - 640) << 2) + wv;    // 0..511
    int b = unit >> 4, chunk = unit & 15;  // 16 chunks of 64 px
    float* fl = fls + (wv << 8);
#pragma unroll
    for (int k = 0; k < 4; ++k) fl[k * 64 + lane] = fl2[(b << 8) + k * 64 + lane];
    const float* base = f2 + (size_t)b * 256 * 1024 + (size_t)chunk * 64 + lane;
    float tot = 0.f, str = 0.f;
#pragma unroll 8
    for (int c = 0; c < 256; ++c) {
      float v = base[(size_t)c << 10];
      tot += v; str = fmaf(v, fl[c], str);
    }
    const float ih = 1.0f / 128.0f;
    float d = sigmoidf((tot - str) * ih) - sigmoidf(str * ih);
    float s = wave_reduce(d * d);
    if (lane == 0) atomicAdd(&ifd2_s[unit & 63], s);
  }
}

// ---------------- K4: finalize ----------------
__global__ void k4_finalize(const float* __restrict__ ws, float* __restrict__ out) {
  float scr0 = 0.f, scr1 = 0.f, ifd0 = 0.f, ifd1 = 0.f, ifd2 = 0.f;
  for (int i = 0; i < 64; ++i) {
    scr0 += ws[i];       scr1 += ws[64 + i];
    ifd0 += ws[128 + i]; ifd1 += ws[192 + i]; ifd2 += ws[256 + i];
  }
  float l_main = ws[320];
  scr0 *= (1.0f / (32.0f * 64.0f * 128.0f * 128.0f));
  scr1 *= (1.0f / (32.0f * 128.0f * 64.0f * 64.0f));
  float l_scr = 0.5f * (scr0 + scr1);
  ifd0 *= (1.0f / (32.0f * 128.0f * 128.0f));
  ifd1 *= (1.0f / (32.0f * 64.0f * 64.0f));
  ifd2 *= (1.0f / (32.0f * 32.0f * 32.0f));
  float l_ifd = (ifd0 + ifd1 + ifd2) * (1.0f / 3.0f);
  float total = l_main + 0.015f * l_scr + 0.015f * l_ifd;
  out[0] = total; out[1] = l_main; out[2] = l_scr; out[3] = l_ifd;
}

extern "C" void kernel_launch(void* const* d_in, const int* in_sizes, int n_in,
                              void* d_out, int out_size, void* d_ws, size_t ws_size,
                              hipStream_t stream) {
  (void)in_sizes; (void)n_in; (void)out_size; (void)ws_size;
  const float* pred   = (const float*)d_in[0];
  const float* feat0  = (const float*)d_in[1];  // 32 x 64 x 128 x 128
  const float* feat1  = (const float*)d_in[2];  // 32 x 128 x 64 x 64
  const float* feat2  = (const float*)d_in[3];  // 32 x 256 x 32 x 32 (teacher)
  const int*   target = (const int*)d_in[4];
  float* out = (float*)d_out;

  // ws layout (floats):
  // [0,64)=scr0 slots [64,128)=scr1 [128,192)=ifd0 [192,256)=ifd1 [256,320)=ifd2 [320]=main
  float* ws = (float*)d_ws;
  float* scr0_s = ws;
  float* scr1_s = ws + 64;
  float* ifd0_s = ws + 128;
  float* ifd1_s = ws + 192;
  float* ifd2_s = ws + 256;
  float* main_a = ws + 320;
  int*   idx0 = (int*)(ws + 384);        // 64
  int*   idx1 = idx0 + 64;               // 128
  float* ns0  = (float*)(idx1 + 128);    // 32*64
  float* ns1  = ns0 + 2048;              // 32*128
  float* ns2  = ns1 + 4096;              // 32*256
  float* fl0  = ns2 + 8192;
  float* fl1  = fl0 + 2048;
  float* fl2  = fl1 + 4096;

  k0_perm<<<1, 256, 0, stream>>>(idx0, idx1, ws);
  k1_pass1<<<3584, 256, 0, stream>>>(feat0, feat1, feat2, idx0, idx1, ns0, ns1, ns2, scr0_s, scr1_s);
  k2_rank_main<<<128, 256, 0, stream>>>(ns0, ns1, ns2, fl0, fl1, fl2, pred, target, main_a);
  k3_pass2<<<768, 256, 0, stream>>>(feat0, feat1, feat2, fl0, fl1, fl2, ifd0_s, ifd1_s, ifd2_s);
  k4_finalize<<<1, 1, 0, stream>>>(ws, out);
}